// Round 15
// baseline (77.171 us; speedup 1.0000x reference)
//
#include <hip/hip_runtime.h>

#define Hc     512
#define Wc     512
#define OH     506
#define OW     506
#define NPIX   (Hc * Wc)
#define BATCH  64
#define CHUNKS 32

#define BH     28                          // output rows per band (4 groups of 7)
#define NBAND  19                          // 18*28=504; band 18: rows 504-505
#define NW     3                           // col-chunks (strips) per image row
#define WPB    4                           // waves (bands) per block
#define BLK_PER_STRIP 5                    // ceil(20/4): bands 0..19 (19 dead)
#define NSTRIP (BATCH * NW)                // 192
#define NBLK   (NSTRIP * BLK_PER_STRIP)    // 960 (%8==0 -> bijective swizzle)
#define STRIPS_PER_XCD (NSTRIP / 8)        // 24
#define NPART  NBLK

typedef float f32x2 __attribute__((ext_vector_type(2)));
typedef float f32x4 __attribute__((ext_vector_type(4)));

// ---------------- Kernel 1: per-(sample,chunk) min/max partials -------------
__global__ __launch_bounds__(256) void mm_part_kernel(
    const float* __restrict__ X, const float* __restrict__ Y,
    float* __restrict__ part)
{
    int blk = blockIdx.x;            // 0 .. BATCH*CHUNKS-1
    int b   = blk >> 5;
    int ch  = blk & 31;
    size_t base = (size_t)b * NPIX + (size_t)ch * (NPIX / CHUNKS);
    const float4* x4 = (const float4*)(X + base);
    const float4* y4 = (const float4*)(Y + base);
    const int n4 = (NPIX / CHUNKS) / 4;   // 2048

    float mn = 1e38f, mx = -1e38f;
    for (int i = threadIdx.x; i < n4; i += 256) {
        float4 a = x4[i];
        float4 c = y4[i];
        mn = fminf(mn, fminf(fminf(a.x, a.y), fminf(a.z, a.w)));
        mx = fmaxf(mx, fmaxf(fmaxf(a.x, a.y), fmaxf(a.z, a.w)));
        mn = fminf(mn, fminf(fminf(c.x, c.y), fminf(c.z, c.w)));
        mx = fmaxf(mx, fmaxf(fmaxf(c.x, c.y), fmaxf(c.z, c.w)));
    }
    #pragma unroll
    for (int off = 1; off < 64; off <<= 1) {
        mn = fminf(mn, __shfl_xor(mn, off, 64));
        mx = fmaxf(mx, __shfl_xor(mx, off, 64));
    }
    __shared__ float smn[4], smx[4];
    int lane = threadIdx.x & 63, wid = threadIdx.x >> 6;
    if (lane == 0) { smn[wid] = mn; smx[wid] = mx; }
    __syncthreads();
    if (threadIdx.x == 0) {
        mn = fminf(fminf(smn[0], smn[1]), fminf(smn[2], smn[3]));
        mx = fmaxf(fmaxf(smx[0], smx[1]), fmaxf(smx[2], smx[3]));
        part[2 * blk]     = mn;
        part[2 * blk + 1] = mx;
    }
}

// ---------------- Kernel 2: ring-buffered streaming SSIM --------------------
// R13 math (verified). NEW: 7-row register ring of raw x,y (static indices via
// full unroll) replaces the outgoing-row re-load: 2 VMEM/iter instead of 4.
__global__ __launch_bounds__(256, 4) void ssim_stream_kernel(
    const float* __restrict__ X, const float* __restrict__ Y,
    const float* __restrict__ mmpart, float* __restrict__ part)
{
    const int lane = threadIdx.x & 63;
    const int wid  = threadIdx.x >> 6;

    // XCD-affine swizzle (bijective: NBLK % 8 == 0)
    const int lin   = blockIdx.x;            // 0..959
    const int xcd   = lin & 7;
    const int slot  = lin >> 3;              // 0..119
    const int strip_local = slot / BLK_PER_STRIP;   // 0..23
    const int blk   = slot - strip_local * BLK_PER_STRIP;  // 0..4
    const int strip = xcd * STRIPS_PER_XCD + strip_local;  // 0..191
    const int img   = strip / NW;
    const int chunk = strip - img * NW;      // 0..2
    const int band  = blk * WPB + wid;       // 0..19 (19 = dead)

    // fold chunk min/max -> C1, C2 (uniform; L2-hot)
    float mn = 1e38f, mx = -1e38f;
    #pragma unroll
    for (int ch = 0; ch < CHUNKS; ++ch) {
        mn = fminf(mn, mmpart[2 * (img * CHUNKS + ch)]);
        mx = fmaxf(mx, mmpart[2 * (img * CHUNKS + ch) + 1]);
    }
    const float dr  = mx - mn;
    const float C1p = 2401.0f * (0.01f * dr) * (0.01f * dr);
    const float C2p = 2401.0f * (0.03f * dr) * (0.03f * dr);
    const f32x2 C1v = {C1p, C1p};
    const f32x2 C2v = {C2p, C2p};
    const f32x2 k49   = {49.0f, 49.0f};
    const f32x2 covn1 = {49.0f / 48.0f, 49.0f / 48.0f};
    const f32x2 covn2 = {2.0f * 49.0f / 48.0f, 2.0f * 49.0f / 48.0f};

    // chunk geometry
    const int cbase  = (chunk == 0) ? 0 : (chunk == 1) ? 248 : 496;
    const int out_lo = (chunk == 0) ? 0 : (chunk == 1) ? 250 : 498;
    const int out_hi = (chunk == 0) ? 249 : (chunk == 1) ? 497 : 505;

    const int col0  = cbase + 4 * lane;             // logical first col
    const int col0c = (col0 < 508) ? col0 : 508;    // clamped, 16B aligned
    f32x2 vm01, vm23;
    {
        float v[4];
        #pragma unroll
        for (int j = 0; j < 4; ++j) {
            int oc = col0 + j;
            v[j] = (oc >= out_lo && oc <= out_hi) ? 1.0f : 0.0f;
        }
        vm01 = (f32x2){v[0], v[1]};
        vm23 = (f32x2){v[2], v[3]};
    }

    const int oy0 = band * BH;
    const int nvalid = OH - oy0 < BH ? OH - oy0 : BH;  // 28, 2 (band 18), <0 dead

    const float* px = X + (size_t)img * NPIX + col0c;
    const float* py = Y + (size_t)img * NPIX + col0c;

    f32x2 acc2 = {0.f, 0.f};

    // horizontal 7-window via prefix-shuffles: 4 DS ops per stat
    #define H7(V, W0, W1, W2, W3)                                            \
    {                                                                        \
        float v0 = V[0].x, v1 = V[0].y, v2 = V[1].x, v3 = V[1].y;            \
        float t01 = v0 + v1, u23 = v2 + v3;                                  \
        float P3 = t01 + v2, P4 = t01 + u23;                                 \
        float A3 = __shfl_down(P3, 1, 64);                                   \
        float A4 = __shfl_down(P4, 1, 64);                                   \
        float B1 = __shfl_down(v0, 2, 64);                                   \
        float B2 = __shfl_down(t01, 2, 64);                                  \
        float cc = u23 + A4;                                                 \
        W0 = P4 + A3;                                                        \
        W1 = cc + v1;                                                        \
        W2 = cc + B1;                                                        \
        W3 = (v3 + A4) + B2;                                                 \
    }

    // 49^2-prescaled SSIM for a packed pair of columns
    #define SSIM2(wx, wy, wp, ws, vmv)                                       \
    {                                                                        \
        f32x2 t1  = wx * wy;                                                 \
        f32x2 sq  = wx * wx + wy * wy;                                       \
        f32x2 F1  = t1 + t1 + C1v;                                           \
        f32x2 d1  = k49 * wp - t1;                                           \
        f32x2 F2  = covn2 * d1 + C2v;                                        \
        f32x2 F3  = sq + C1v;                                                \
        f32x2 d2  = k49 * ws - sq;                                           \
        f32x2 F4  = covn1 * d2 + C2v;                                        \
        f32x2 den = F3 * F4;                                                 \
        f32x2 num = F1 * F2;                                                 \
        f32x2 rv  = {__builtin_amdgcn_rcpf(den.x),                           \
                     __builtin_amdgcn_rcpf(den.y)};                          \
        acc2 += num * rv * vmv;                                              \
    }

    if (nvalid > 0) {                       // wave-uniform; no barriers inside
        // packed running vertical sums + 7-row raw ring (static indices)
        f32x2 Vx[2]  = {{0,0},{0,0}}, Vy[2]  = {{0,0},{0,0}};
        f32x2 Vxy[2] = {{0,0},{0,0}}, Vss[2] = {{0,0},{0,0}};
        f32x2 rgx[7][2], rgy[7][2];

        // prologue: rows oy0..oy0+5 -> ring slots 0..5 (max row 509)
        #pragma unroll
        for (int j = 0; j < 6; ++j) {
            f32x4 xa = *(const f32x4*)(px + (size_t)(oy0 + j) * Wc);
            f32x4 ya = *(const f32x4*)(py + (size_t)(oy0 + j) * Wc);
            f32x2 xl = xa.lo, xh = xa.hi, yl = ya.lo, yh = ya.hi;
            Vx[0] += xl; Vx[1] += xh; Vy[0] += yl; Vy[1] += yh;
            Vxy[0] += xl * yl; Vxy[1] += xh * yh;
            Vss[0] += xl * xl + yl * yl; Vss[1] += xh * xh + yh * yh;
            rgx[j][0] = xl; rgx[j][1] = xh;
            rgy[j][0] = yl; rgy[j][1] = yh;
        }

        #pragma unroll
        for (int g = 0; g < 4; ++g) {
            #pragma unroll
            for (int k = 0; k < 7; ++k) {
                const int tt = g * 7 + k;
                if (tt < nvalid) {          // wave-uniform
                    // incoming row oy0+tt+6 (<= 511 guaranteed by guard)
                    f32x4 xa = *(const f32x4*)(px + (size_t)(oy0 + tt + 6) * Wc);
                    f32x4 ya = *(const f32x4*)(py + (size_t)(oy0 + tt + 6) * Wc);
                    f32x2 xl = xa.lo, xh = xa.hi, yl = ya.lo, yh = ya.hi;
                    Vx[0] += xl; Vx[1] += xh; Vy[0] += yl; Vy[1] += yh;
                    Vxy[0] += xl * yl; Vxy[1] += xh * yh;
                    Vss[0] += xl * xl + yl * yl; Vss[1] += xh * xh + yh * yh;

                    float Wx0, Wx1, Wx2, Wx3;  H7(Vx,  Wx0, Wx1, Wx2, Wx3)
                    float Wy0, Wy1, Wy2, Wy3;  H7(Vy,  Wy0, Wy1, Wy2, Wy3)
                    float Wp0, Wp1, Wp2, Wp3;  H7(Vxy, Wp0, Wp1, Wp2, Wp3)
                    float Ws0, Ws1, Ws2, Ws3;  H7(Vss, Ws0, Ws1, Ws2, Ws3)
                    f32x2 wx01 = {Wx0, Wx1}, wx23 = {Wx2, Wx3};
                    f32x2 wy01 = {Wy0, Wy1}, wy23 = {Wy2, Wy3};
                    f32x2 wp01 = {Wp0, Wp1}, wp23 = {Wp2, Wp3};
                    f32x2 ws01 = {Ws0, Ws1}, ws23 = {Ws2, Ws3};
                    SSIM2(wx01, wy01, wp01, ws01, vm01)
                    SSIM2(wx23, wy23, wp23, ws23, vm23)

                    // subtract outgoing row tt from ring slot k (static)
                    {
                        f32x2 ox0 = rgx[k][0], ox1 = rgx[k][1];
                        f32x2 oy_ = rgy[k][0], oy1 = rgy[k][1];
                        Vx[0] -= ox0; Vx[1] -= ox1;
                        Vy[0] -= oy_; Vy[1] -= oy1;
                        Vxy[0] -= ox0 * oy_; Vxy[1] -= ox1 * oy1;
                        Vss[0] -= ox0 * ox0 + oy_ * oy_;
                        Vss[1] -= ox1 * ox1 + oy1 * oy1;
                    }
                    // store incoming row (tt+6) into slot (k+6)%7 (static)
                    rgx[(k + 6) % 7][0] = xl; rgx[(k + 6) % 7][1] = xh;
                    rgy[(k + 6) % 7][0] = yl; rgy[(k + 6) % 7][1] = yh;
                }
            }
        }
    }

    #undef SSIM2
    #undef H7

    float acc = acc2.x + acc2.y;
    // deterministic wave reduce + cross-wave LDS fold (one partial per block)
    #pragma unroll
    for (int off = 1; off < 64; off <<= 1)
        acc += __shfl_xor(acc, off, 64);
    __shared__ float sacc[4];
    if (lane == 0) sacc[wid] = acc;
    __syncthreads();
    if (threadIdx.x == 0)
        part[lin] = (sacc[0] + sacc[1]) + (sacc[2] + sacc[3]);
}

// ---------------- Kernel 3: final deterministic f64 reduction ---------------
__global__ __launch_bounds__(1024) void final_reduce_kernel(
    const float* __restrict__ part, float* __restrict__ out)
{
    __shared__ double sd[1024];
    double s = 0.0;
    for (int i = threadIdx.x; i < NPART; i += 1024)
        s += (double)part[i];
    sd[threadIdx.x] = s;
    __syncthreads();
    for (int off = 512; off > 0; off >>= 1) {
        if (threadIdx.x < off) sd[threadIdx.x] += sd[threadIdx.x + off];
        __syncthreads();
    }
    if (threadIdx.x == 0)
        out[0] = (float)(sd[0] / ((double)BATCH * OH * OW));
}

extern "C" void kernel_launch(void* const* d_in, const int* in_sizes, int n_in,
                              void* d_out, int out_size, void* d_ws, size_t ws_size,
                              hipStream_t stream) {
    const float* X = (const float*)d_in[0];
    const float* Y = (const float*)d_in[1];
    float* out = (float*)d_out;
    float* ws  = (float*)d_ws;

    float* mmpart = ws;                   // 2 * BATCH * CHUNKS = 4096 floats
    float* part   = ws + 4096;            // NPART = 960 floats

    mm_part_kernel<<<BATCH * CHUNKS, 256, 0, stream>>>(X, Y, mmpart);
    ssim_stream_kernel<<<NBLK, 64 * WPB, 0, stream>>>(X, Y, mmpart, part);
    final_reduce_kernel<<<1, 1024, 0, stream>>>(part, out);
}